// Round 5
// baseline (250.334 us; speedup 1.0000x reference)
//
#include <hip/hip_runtime.h>
#include <math.h>

#define HH 512
#define WW 512
#define NCH 48
#define HWPIX (HH * WW)

#define TW 16            // tile width (pixels)
#define TH 8             // tile height
#define HW_HALO 18       // TW + 2
#define HH_HALO 10       // TH + 2
#define NHALO (HW_HALO * HH_HALO)   // 180 halo pixels
#define ASTRIDE 12       // floats per pixel in packed A (9 + 3 pad, 16B-aligned)

// LDS x-tile layout (DMA-native): chunk-block (w = haloidx>>6, i = ch-chunk)
// holds 64 lanes' float4 contiguously + 1 pad slot -> stride 65 float4.
//   addr4(p, ch) = (p>>6)*780 + ch*65 + (p&63)        [780 = 12*65]
// Pad makes ch-step (65) odd mod 8 -> quad/pair read pattern hits every bank
// exactly 8x (the wave64-b128 minimum): conflict-free.
#define BLK_STRIDE 65
#define WAVE_STRIDE 780  // 12 * BLK_STRIDE

// ---------------------------------------------------------------------------
// global -> LDS direct DMA helpers (dest = wave-uniform base + lane*size)
// ---------------------------------------------------------------------------
__device__ __forceinline__ void gl2lds16(const float4* g, float4* l) {
  __builtin_amdgcn_global_load_lds(
      (const __attribute__((address_space(1))) void*)g,
      (__attribute__((address_space(3))) void*)l, 16, 0, 0);
}
__device__ __forceinline__ void gl2lds4(const float* g, float* l) {
  __builtin_amdgcn_global_load_lds(
      (const __attribute__((address_space(1))) void*)g,
      (__attribute__((address_space(3))) void*)l, 4, 0, 0);
}

// ---------------------------------------------------------------------------
// Kernel 1: precompute packed stencil weights A (9 used + 3 pad floats/pixel,
// border masks + 1/dg + MSQ folded in) AND the initial logsumexp of v.
// ---------------------------------------------------------------------------
__global__ __launch_bounds__(256) void compute_A_lse_kernel(
    const float* __restrict__ Dt, const float* __restrict__ dg,
    const float* __restrict__ x, float* __restrict__ A,
    float* __restrict__ lse0) {
  int pix = blockIdx.x * blockDim.x + threadIdx.x;
  int h = pix >> 9;
  int w = pix & (WW - 1);
  int hm = (h == 0) ? HH - 1 : h - 1;
  int hp = (h == HH - 1) ? 0 : h + 1;
  int wm = (w == 0) ? WW - 1 : w - 1;
  int wp = (w == WW - 1) ? 0 : w + 1;

  float aC, cC, bC, cL, bL, cR, bR, aU, bU, aD, bD;
  float bUL, bUR, bDL, bDR;
  {
    int p;
    p = (h * WW + w) * 3;   aC = Dt[p]; cC = Dt[p + 1]; bC = Dt[p + 2];
    p = (h * WW + wm) * 3;  cL = Dt[p + 1]; bL = Dt[p + 2];
    p = (h * WW + wp) * 3;  cR = Dt[p + 1]; bR = Dt[p + 2];
    p = (hm * WW + w) * 3;  aU = Dt[p]; bU = Dt[p + 2];
    p = (hp * WW + w) * 3;  aD = Dt[p]; bD = Dt[p + 2];
    p = (hm * WW + wm) * 3; bUL = Dt[p + 2];
    p = (hm * WW + wp) * 3; bUR = Dt[p + 2];
    p = (hp * WW + wm) * 3; bDL = Dt[p + 2];
    p = (hp * WW + wp) * 3; bDR = Dt[p + 2];
  }

  float A0 = (fabsf(bDL) - bDL + fabsf(bC) - bC) * 0.25f;
  float A1 = (cL + cC - fabsf(bL) - fabsf(bC)) * 0.5f;
  float A2 = (fabsf(bUL) + bUL + fabsf(bC) + bC) * 0.25f;
  float A3 = (aD + aC - fabsf(bD) - fabsf(bC)) * 0.5f;
  float A4 = -(aD + 2.f * aC + aU) * 0.5f
             - (fabsf(bDL) - bDL + fabsf(bUL) + bUL) * 0.25f
             - (fabsf(bDR) + bDR + fabsf(bUR) - bUR) * 0.25f
             + (fabsf(bD) + fabsf(bU) + fabsf(bR) + fabsf(bL) + 2.f * fabsf(bC)) * 0.5f
             - (cR + 2.f * cC + cL) * 0.5f;
  float A5 = (aU + aC - fabsf(bU) - fabsf(bC)) * 0.5f;
  float A6 = (fabsf(bDR) + bDR + fabsf(bC) + bC) * 0.25f;
  float A7 = (cR + cC - fabsf(bR) - fabsf(bC)) * 0.5f;
  float A8 = (fabsf(bUR) - bUR + fabsf(bC) - bC) * 0.25f;

  bool ru = (h > 0), rd = (h < HH - 1), cl = (w > 0), cr = (w < WW - 1);
  if (!(ru && cl)) A0 = 0.f;
  if (!ru)         A1 = 0.f;
  if (!(ru && cr)) A2 = 0.f;
  if (!cl)         A3 = 0.f;
  if (!cr)         A5 = 0.f;
  if (!(rd && cl)) A6 = 0.f;
  if (!rd)         A7 = 0.f;
  if (!(rd && cr)) A8 = 0.f;

  float g = 1.0f / dg[pix];
  float4* Ao = (float4*)A + (size_t)pix * 3;
  Ao[0] = make_float4(A0 * g, A1 * g, A2 * g, A3 * g);
  Ao[1] = make_float4(A4 * g + 0.1f, A5 * g, A6 * g, A7 * g);
  Ao[2] = make_float4(A8 * g, 0.f, 0.f, 0.f);

  // ---- initial lse of v --------------------------------------------------
  const float4* xv = (const float4*)x + (size_t)pix * 12;
  float4 u[12];
#pragma unroll
  for (int i = 0; i < 12; i++) u[i] = xv[i];
  float4 mv = u[0];
#pragma unroll
  for (int i = 1; i < 12; i++) {
    mv.x = fmaxf(mv.x, u[i].x); mv.y = fmaxf(mv.y, u[i].y);
    mv.z = fmaxf(mv.z, u[i].z); mv.w = fmaxf(mv.w, u[i].w);
  }
  float m = fmaxf(fmaxf(mv.x, mv.y), fmaxf(mv.z, mv.w));
  float sx = 0.f, sy = 0.f, sz = 0.f, sw = 0.f;
#pragma unroll
  for (int i = 0; i < 12; i++) {
    sx += __expf(u[i].x - m); sy += __expf(u[i].y - m);
    sz += __expf(u[i].z - m); sw += __expf(u[i].w - m);
  }
  lse0[pix] = m + __logf((sx + sy) + (sz + sw));
}

// ---------------------------------------------------------------------------
// Fused Euler step.
// Phase 1 is pure DMA: threads 0..179 issue 12x global_load_lds(16B) for
//   their halo pixel's 48 channels plus 1x global_load_lds(4B) for its lse
//   (computed by the PREVIOUS step's epilogue / init kernel), then barrier.
//   No exp chain, no VGPR round-trip, no ds_writes on the critical path.
// Phase 2: quad handles a pixel pair; 3x4 LDS patch serves both stencils;
//   lse taps from lse_s.
// Epilogue: computes lse of the NEW x per pixel (quad shuffle reduce over the
//   r-values already in registers) and stores to lse_out for the next step.
//   NOTE (R2 bug): the pixel-1 max reduce must cover its .w components too —
//   a missed max makes exp() overflow at this problem's 1e8-rail magnitudes.
// ---------------------------------------------------------------------------
__global__ __launch_bounds__(256, 4) void step_fused_kernel(
    const float* __restrict__ x, const float* __restrict__ A,
    const float* __restrict__ hinv, float* __restrict__ xn,
    const float* __restrict__ lse_in, float* __restrict__ lse_out,
    int write_lse) {
  __shared__ float4 tile4[36 * BLK_STRIDE];  // 36*65*16 = 37,440 B
  __shared__ float lse_s[192];               // + 768 B (180 used)

  int b = blockIdx.x;
  int tile_id = (b & 7) * 256 + (b >> 3);    // XCD-band swizzle
  int th0 = (tile_id >> 5) * TH;
  int tw0 = (tile_id & 31) * TW;

  int t = threadIdx.x;
  int sub = t & 3;                            // chunk-interleave lane
  int pair = t >> 2;                          // 0..63
  int pr = pair >> 3;                         // tile row 0..7
  int pc0 = (pair & 7) * 2;                   // even tile col 0..14
  int pix0 = (th0 + pr) * WW + (tw0 + pc0);
  int pix1 = pix0 + 1;

  // ---- Phase 1: DMA halo x + halo lse into LDS --------------------------
  if (t < NHALO) {
    int r = t / HW_HALO;
    int c = t - r * HW_HALO;
    int gh = (th0 + r - 1) & (HH - 1);       // periodic wrap
    int gw = (tw0 + c - 1) & (WW - 1);
    int gp = gh * WW + gw;
    const float4* src = (const float4*)x + (size_t)gp * 12;
    int wv = t >> 6;                          // wave id 0..2 (uniform in wave)
    float4* dst = tile4 + wv * WAVE_STRIDE;
#pragma unroll
    for (int i = 0; i < 12; i++)
      gl2lds16(src + i, dst + i * BLK_STRIDE);
    gl2lds4(lse_in + gp, lse_s + (wv << 6));
  }

  // ---- prefetch packed stencil weights + hinv (pre-barrier) -------------
  const float4* ap0 = (const float4*)A + (size_t)pix0 * 3;
  const float4* ap1 = (const float4*)A + (size_t)pix1 * 3;
  float4 wA0 = ap0[0], wB0 = ap0[1], wC0 = ap0[2];
  float4 wA1 = ap1[0], wB1 = ap1[1], wC1 = ap1[2];
  const float2* hp = (const float2*)(hinv + (size_t)pix0 * 3);
  float2 h01 = hp[0], h23 = hp[1], h45 = hp[2];

  __syncthreads();   // drains vmcnt -> DMA data visible

  // ---- Phase 2: pixel-pair compute --------------------------------------
  float wt0[9] = {wA0.x, wA0.y, wA0.z, wA0.w, wB0.x, wB0.y, wB0.z, wB0.w, wC0.x};
  float wt1[9] = {wA1.x, wA1.y, wA1.z, wA1.w, wB1.x, wB1.y, wB1.z, wB1.w, wC1.x};
  float ha0 = h01.x, hc0 = h01.y, hb0 = h23.x;
  float ha1 = h23.y, hc1 = h45.x, hb1 = h45.y;

  // lse taps (halo coords: center of px0 = (pr+1, pc0+1))
  int lc0 = (pr + 1) * HW_HALO + (pc0 + 1);
  float l0C = lse_s[lc0];
  float l0R = lse_s[lc0 + 1];                 // = l1C
  float l1R = lse_s[lc0 + 2];
  float l0D = lse_s[lc0 + HW_HALO];
  float l1D = lse_s[lc0 + HW_HALO + 1];
  float dld0 = l0C - l0D, dlr0 = l0C - l0R;
  float dld1 = l0R - l1D, dlr1 = l0R - l1R;

  // LDS base float4-offsets of the 3x4 patch (ch added per read)
  int base4[3][4];
#pragma unroll
  for (int dr = 0; dr < 3; dr++)
#pragma unroll
    for (int dc = 0; dc < 4; dc++) {
      int p = (pr + dr) * HW_HALO + pc0 + dc;
      base4[dr][dc] = (p >> 6) * WAVE_STRIDE + (p & 63);
    }

  float4 vals0[3], vals1[3];
  float sum0 = 0.f, sum1 = 0.f;
#pragma unroll
  for (int j = 0; j < 3; j++) {
    int ch = j * 4 + sub;
    int choff = ch * BLK_STRIDE;
    float4 q[3][4];
#pragma unroll
    for (int dr = 0; dr < 3; dr++)
#pragma unroll
      for (int dc = 0; dc < 4; dc++) q[dr][dc] = tile4[base4[dr][dc] + choff];

    float4 val0, val1;
#define COMP(f)                                                                \
    {                                                                          \
      float s0_ = wt0[0] * q[0][0].f + wt0[1] * q[0][1].f + wt0[2] * q[0][2].f \
                + wt0[3] * q[1][0].f + wt0[4] * q[1][1].f + wt0[5] * q[1][2].f \
                + wt0[6] * q[2][0].f + wt0[7] * q[2][1].f + wt0[8] * q[2][2].f;\
      float v00 = q[2][1].f - q[1][1].f + dld0;                                \
      float v10 = q[1][2].f - q[1][1].f + dlr0;                                \
      float vv0 = s0_ + 0.5f * (ha0 * v00 * v00 + hc0 * v10 * v10) +           \
                  hb0 * (v00 * v10);                                           \
      val0.f = vv0; sum0 += vv0;                                               \
      float s1_ = wt1[0] * q[0][1].f + wt1[1] * q[0][2].f + wt1[2] * q[0][3].f \
                + wt1[3] * q[1][1].f + wt1[4] * q[1][2].f + wt1[5] * q[1][3].f \
                + wt1[6] * q[2][1].f + wt1[7] * q[2][2].f + wt1[8] * q[2][3].f;\
      float v01 = q[2][2].f - q[1][2].f + dld1;                                \
      float v11 = q[1][3].f - q[1][2].f + dlr1;                                \
      float vv1 = s1_ + 0.5f * (ha1 * v01 * v01 + hc1 * v11 * v11) +           \
                  hb1 * (v01 * v11);                                           \
      val1.f = vv1; sum1 += vv1;                                               \
    }
    COMP(x) COMP(y) COMP(z) COMP(w)
#undef COMP
    vals0[j] = val0;
    vals1[j] = val1;
  }

  // channel mean across the 4-thread quad (48 channels per pixel)
  sum0 += __shfl_xor(sum0, 1); sum0 += __shfl_xor(sum0, 2);
  sum1 += __shfl_xor(sum1, 1); sum1 += __shfl_xor(sum1, 2);
  float mean0 = sum0 * (1.0f / 48.0f);
  float mean1 = sum1 * (1.0f / 48.0f);

  // centers re-read from LDS; keep the r-values for the lse epilogue
  int cb0 = (lc0 >> 6) * WAVE_STRIDE + (lc0 & 63);
  int lc1 = lc0 + 1;
  int cb1 = (lc1 >> 6) * WAVE_STRIDE + (lc1 & 63);
  float4* op0 = (float4*)(xn + (size_t)pix0 * NCH);
  float4* op1 = op0 + 12;
  float4 rr0[3], rr1[3];
#pragma unroll
  for (int j = 0; j < 3; j++) {
    int ch = j * 4 + sub;
    int choff = ch * BLK_STRIDE;
    float4 c0 = tile4[cb0 + choff];
    float4 c1 = tile4[cb1 + choff];
    float4 r0, r1;
    r0.x = c0.x + 0.2f * fminf(fmaxf(vals0[j].x - mean0, -1e8f), 1e8f);
    r0.y = c0.y + 0.2f * fminf(fmaxf(vals0[j].y - mean0, -1e8f), 1e8f);
    r0.z = c0.z + 0.2f * fminf(fmaxf(vals0[j].z - mean0, -1e8f), 1e8f);
    r0.w = c0.w + 0.2f * fminf(fmaxf(vals0[j].w - mean0, -1e8f), 1e8f);
    r1.x = c1.x + 0.2f * fminf(fmaxf(vals1[j].x - mean1, -1e8f), 1e8f);
    r1.y = c1.y + 0.2f * fminf(fmaxf(vals1[j].y - mean1, -1e8f), 1e8f);
    r1.z = c1.z + 0.2f * fminf(fmaxf(vals1[j].z - mean1, -1e8f), 1e8f);
    r1.w = c1.w + 0.2f * fminf(fmaxf(vals1[j].w - mean1, -1e8f), 1e8f);
    op0[ch] = r0;
    op1[ch] = r1;
    rr0[j] = r0;
    rr1[j] = r1;
  }

  // ---- Epilogue: lse of the NEW x (for the next step) -------------------
  if (write_lse) {
    float4 m4;
    m4.x = fmaxf(fmaxf(rr0[0].x, rr0[1].x), rr0[2].x);
    m4.y = fmaxf(fmaxf(rr0[0].y, rr0[1].y), rr0[2].y);
    m4.z = fmaxf(fmaxf(rr0[0].z, rr0[1].z), rr0[2].z);
    m4.w = fmaxf(fmaxf(rr0[0].w, rr0[1].w), rr0[2].w);
    float m0 = fmaxf(fmaxf(m4.x, m4.y), fmaxf(m4.z, m4.w));
    m4.x = fmaxf(fmaxf(rr1[0].x, rr1[1].x), rr1[2].x);
    m4.y = fmaxf(fmaxf(rr1[0].y, rr1[1].y), rr1[2].y);
    m4.z = fmaxf(fmaxf(rr1[0].z, rr1[1].z), rr1[2].z);
    m4.w = fmaxf(fmaxf(rr1[0].w, rr1[1].w), rr1[2].w);   // FIXED (was partial-reduce typo)
    float m1 = fmaxf(fmaxf(m4.x, m4.y), fmaxf(m4.z, m4.w));
    m0 = fmaxf(m0, __shfl_xor(m0, 1)); m0 = fmaxf(m0, __shfl_xor(m0, 2));
    m1 = fmaxf(m1, __shfl_xor(m1, 1)); m1 = fmaxf(m1, __shfl_xor(m1, 2));
    float s0 = 0.f, s1 = 0.f;
#pragma unroll
    for (int j = 0; j < 3; j++) {
      s0 += __expf(rr0[j].x - m0) + __expf(rr0[j].y - m0) +
            __expf(rr0[j].z - m0) + __expf(rr0[j].w - m0);
      s1 += __expf(rr1[j].x - m1) + __expf(rr1[j].y - m1) +
            __expf(rr1[j].z - m1) + __expf(rr1[j].w - m1);
    }
    s0 += __shfl_xor(s0, 1); s0 += __shfl_xor(s0, 2);
    s1 += __shfl_xor(s1, 1); s1 += __shfl_xor(s1, 2);
    if (sub == 0) {
      lse_out[pix0] = m0 + __logf(s0);
      lse_out[pix1] = m1 + __logf(s1);
    }
  }
}

// ---------------------------------------------------------------------------
// Host launcher.  inputs: v (H,W,48), Dt (H,W,3), dg (H,W,1), hinv (H,W,3)
// ws layout: A[12*HW] | xbuf[48*HW] | lse0[HW] | lse1[HW]   (~65 MB)
// x ping-pong: v -> out -> ws -> out -> ws -> out  (5 steps)
// lse ping-pong: init->lse0; step s reads lse[s&1], writes lse[(s+1)&1]
// ---------------------------------------------------------------------------
extern "C" void kernel_launch(void* const* d_in, const int* in_sizes, int n_in,
                              void* d_out, int out_size, void* d_ws, size_t ws_size,
                              hipStream_t stream) {
  const float* v    = (const float*)d_in[0];
  const float* Dt   = (const float*)d_in[1];
  const float* dg   = (const float*)d_in[2];
  const float* hinv = (const float*)d_in[3];
  float* out = (float*)d_out;

  float* A    = (float*)d_ws;
  float* xbuf = A + (size_t)ASTRIDE * HWPIX;
  float* lse0 = xbuf + (size_t)NCH * HWPIX;
  float* lse1 = lse0 + HWPIX;

  compute_A_lse_kernel<<<dim3(HWPIX / 256), dim3(256), 0, stream>>>(
      Dt, dg, v, A, lse0);

  const float* cur = v;
  float* nxt = out;
  float* lsebuf[2] = {lse0, lse1};
  for (int s = 0; s < 5; s++) {
    step_fused_kernel<<<dim3(HWPIX / 128), dim3(256), 0, stream>>>(
        cur, A, hinv, nxt, lsebuf[s & 1], lsebuf[(s + 1) & 1], (s < 4) ? 1 : 0);
    if (s == 0) {
      cur = out;
      nxt = xbuf;
    } else {
      float* t = (float*)cur;
      cur = nxt;
      nxt = t;
    }
  }
}

// Round 6
// 209.797 us; speedup vs baseline: 1.1932x; 1.1932x over previous
//
#include <hip/hip_runtime.h>
#include <math.h>

#define HH 512
#define WW 512
#define NCH 48
#define HWPIX (HH * WW)

#define TW 16            // tile width (pixels)
#define TH 8             // tile height
#define HW_HALO 18       // TW + 2
#define HH_HALO 10       // TH + 2
#define NHALO (HW_HALO * HH_HALO)   // 180 halo pixels
#define PSTRIDE 13       // float4 slots per halo pixel (12 + 1 pad)
#define ASTRIDE 12       // floats per pixel in packed A (9 + 3 pad, 16B-aligned)

// ---------------------------------------------------------------------------
// Kernel 1: precompute the 9 per-pixel stencil weights from Dt, with
//   - border zero-padding masks folded in (conv is SAME/zero-pad),
//   - 1/dg folded in, MSQ=0.1 folded into the center weight.
// Dt layout: (H, W, 3) = (a, c, b); rolls are PERIODIC (jnp.roll).
// A stored PIXEL-MAJOR, 12 floats per pixel (slots 0..8 used, 9..11 pad):
//   A[pix*12 + k] multiplies x[h-1+k/3, w-1+k%3].  One pixel's weights are
//   3 aligned float4 loads.
// ---------------------------------------------------------------------------
__global__ __launch_bounds__(256) void compute_A_kernel(
    const float* __restrict__ Dt, const float* __restrict__ dg,
    float* __restrict__ A) {
  int pix = blockIdx.x * blockDim.x + threadIdx.x;
  int h = pix >> 9;
  int w = pix & (WW - 1);
  int hm = (h == 0) ? HH - 1 : h - 1;
  int hp = (h == HH - 1) ? 0 : h + 1;
  int wm = (w == 0) ? WW - 1 : w - 1;
  int wp = (w == WW - 1) ? 0 : w + 1;

  float aC, cC, bC, cL, bL, cR, bR, aU, bU, aD, bD;
  float bUL, bUR, bDL, bDR;
  {
    int p;
    p = (h * WW + w) * 3;   aC = Dt[p]; cC = Dt[p + 1]; bC = Dt[p + 2];
    p = (h * WW + wm) * 3;  cL = Dt[p + 1]; bL = Dt[p + 2];
    p = (h * WW + wp) * 3;  cR = Dt[p + 1]; bR = Dt[p + 2];
    p = (hm * WW + w) * 3;  aU = Dt[p]; bU = Dt[p + 2];
    p = (hp * WW + w) * 3;  aD = Dt[p]; bD = Dt[p + 2];
    p = (hm * WW + wm) * 3; bUL = Dt[p + 2];
    p = (hm * WW + wp) * 3; bUR = Dt[p + 2];
    p = (hp * WW + wm) * 3; bDL = Dt[p + 2];
    p = (hp * WW + wp) * 3; bDR = Dt[p + 2];
  }

  float A0 = (fabsf(bDL) - bDL + fabsf(bC) - bC) * 0.25f;
  float A1 = (cL + cC - fabsf(bL) - fabsf(bC)) * 0.5f;
  float A2 = (fabsf(bUL) + bUL + fabsf(bC) + bC) * 0.25f;
  float A3 = (aD + aC - fabsf(bD) - fabsf(bC)) * 0.5f;
  float A4 = -(aD + 2.f * aC + aU) * 0.5f
             - (fabsf(bDL) - bDL + fabsf(bUL) + bUL) * 0.25f
             - (fabsf(bDR) + bDR + fabsf(bUR) - bUR) * 0.25f
             + (fabsf(bD) + fabsf(bU) + fabsf(bR) + fabsf(bL) + 2.f * fabsf(bC)) * 0.5f
             - (cR + 2.f * cC + cL) * 0.5f;
  float A5 = (aU + aC - fabsf(bU) - fabsf(bC)) * 0.5f;
  float A6 = (fabsf(bDR) + bDR + fabsf(bC) + bC) * 0.25f;
  float A7 = (cR + cC - fabsf(bR) - fabsf(bC)) * 0.5f;
  float A8 = (fabsf(bUR) - bUR + fabsf(bC) - bC) * 0.25f;

  bool ru = (h > 0), rd = (h < HH - 1), cl = (w > 0), cr = (w < WW - 1);
  if (!(ru && cl)) A0 = 0.f;
  if (!ru)         A1 = 0.f;
  if (!(ru && cr)) A2 = 0.f;
  if (!cl)         A3 = 0.f;
  if (!cr)         A5 = 0.f;
  if (!(rd && cl)) A6 = 0.f;
  if (!rd)         A7 = 0.f;
  if (!(rd && cr)) A8 = 0.f;

  float g = 1.0f / dg[pix];
  float4* Ao = (float4*)A + (size_t)pix * 3;
  Ao[0] = make_float4(A0 * g, A1 * g, A2 * g, A3 * g);
  Ao[1] = make_float4(A4 * g + 0.1f, A5 * g, A6 * g, A7 * g);
  Ao[2] = make_float4(A8 * g, 0.f, 0.f, 0.f);
}

// ---------------------------------------------------------------------------
// Fused Euler step, 16x8 tile, 2-pixel register blocking, lse-once staging.
// Phase 1: threads 0..179 each stage one halo pixel's 12 float4 from global
//   (periodic wrap) into LDS AND compute its 48-channel logsumexp in-register.
//   The load->exp-chain interleave is the latency hiding (R5 lesson: pure-DMA
//   staging with no own-thread work exposed raw load latency, +6 us/step).
//   lse sum uses 4 parallel accumulators + float4 max tree (shorter dep chain
//   than the serial 48-add version).
//   A (packed, 3x float4) + hinv (3x float2) prefetched pre-barrier.
// Phase 2: quad (4 threads, sub = interleaved chunk j*4+sub) handles a
//   horizontally-adjacent pixel PAIR: 3x4 LDS patch per chunk serves both
//   pixels' 3x3 stencils.
//   val = sum_k Aeff[k]*x[nbr_k] + 0.5*(ha*v0^2 + hc*v1^2) + hb*v0*v1
//   v0 = logp[h+1,w]-logp[h,w], v1 = logp[h,w+1]-logp[h,w]  (periodic)
//   x_next = x + 0.2 * clip(val - mean_ch(val), +-1e8)
// XCD-band swizzle: XCD k (= b%8) gets tile rows [8k,8k+8) = pixel rows
// [64k, 64k+64), keeping vertical halo reuse inside one per-XCD L2.
// ---------------------------------------------------------------------------
__global__ __launch_bounds__(256, 4) void step_fused_kernel(
    const float* __restrict__ x, const float* __restrict__ A,
    const float* __restrict__ hinv, float* __restrict__ xn) {
  __shared__ float4 tile[NHALO * PSTRIDE];   // 180*13*16 = 37,440 B
  __shared__ float lse_s[NHALO];             // + 720 B

  int b = blockIdx.x;
  int tile_id = (b & 7) * 256 + (b >> 3);    // 2048 tiles, 64 rows x 32 cols
  int th0 = (tile_id >> 5) * TH;
  int tw0 = (tile_id & 31) * TW;

  int t = threadIdx.x;
  // phase-2 indices computed up-front (needed for the prefetch)
  int sub = t & 3;                            // interleaved chunk set
  int pair = t >> 2;                          // 0..63
  int pr = pair >> 3;                         // tile row 0..7
  int pc0 = (pair & 7) * 2;                   // even tile col 0..14
  int pix0 = (th0 + pr) * WW + (tw0 + pc0);
  int pix1 = pix0 + 1;

  // ---- Phase 1a: issue halo staging loads (feeds lse + LDS) -------------
  float4 v[12];
  bool stager = (t < NHALO);
  if (stager) {
    int r = t / HW_HALO;
    int c = t - r * HW_HALO;
    int gh = (th0 + r - 1) & (HH - 1);       // periodic wrap
    int gw = (tw0 + c - 1) & (WW - 1);
    const float4* src = (const float4*)x + (size_t)(gh * WW + gw) * 12;
#pragma unroll
    for (int i = 0; i < 12; i++) v[i] = src[i];
  }

  // ---- Phase 1b: prefetch packed stencil weights + hinv (pre-barrier) ----
  const float4* ap0 = (const float4*)A + (size_t)pix0 * 3;
  const float4* ap1 = (const float4*)A + (size_t)pix1 * 3;
  float4 wA0 = ap0[0], wB0 = ap0[1], wC0 = ap0[2];
  float4 wA1 = ap1[0], wB1 = ap1[1], wC1 = ap1[2];
  // 6 consecutive floats for the pair; pix0 is even so base is 8B-aligned
  const float2* hp = (const float2*)(hinv + (size_t)pix0 * 3);
  float2 h01 = hp[0], h23 = hp[1], h45 = hp[2];

  // ---- Phase 1c: lse (4-lane-parallel chains) + LDS staging writes ------
  if (stager) {
    float4 mv = v[0];
#pragma unroll
    for (int i = 1; i < 12; i++) {
      mv.x = fmaxf(mv.x, v[i].x); mv.y = fmaxf(mv.y, v[i].y);
      mv.z = fmaxf(mv.z, v[i].z); mv.w = fmaxf(mv.w, v[i].w);
    }
    float m = fmaxf(fmaxf(mv.x, mv.y), fmaxf(mv.z, mv.w));
    float sx = 0.f, sy = 0.f, sz = 0.f, sw = 0.f;
#pragma unroll
    for (int i = 0; i < 12; i++) {
      sx += __expf(v[i].x - m); sy += __expf(v[i].y - m);
      sz += __expf(v[i].z - m); sw += __expf(v[i].w - m);
      tile[t * PSTRIDE + i] = v[i];
    }
    lse_s[t] = m + __logf((sx + sy) + (sz + sw));
  }
  __syncthreads();

  // ---- Phase 2: pixel-pair compute --------------------------------------
  float wt0[9] = {wA0.x, wA0.y, wA0.z, wA0.w, wB0.x, wB0.y, wB0.z, wB0.w, wC0.x};
  float wt1[9] = {wA1.x, wA1.y, wA1.z, wA1.w, wB1.x, wB1.y, wB1.z, wB1.w, wC1.x};
  float ha0 = h01.x, hc0 = h01.y, hb0 = h23.x;
  float ha1 = h23.y, hc1 = h45.x, hb1 = h45.y;

  // lse taps (halo coords: center of px0 = (pr+1, pc0+1))
  int lc0 = (pr + 1) * HW_HALO + (pc0 + 1);
  float l0C = lse_s[lc0];
  float l0R = lse_s[lc0 + 1];                 // = l1C
  float l1R = lse_s[lc0 + 2];
  float l0D = lse_s[lc0 + HW_HALO];
  float l1D = lse_s[lc0 + HW_HALO + 1];
  float dld0 = l0C - l0D, dlr0 = l0C - l0R;
  float dld1 = l0R - l1D, dlr1 = l0R - l1R;

  // LDS float4-offsets of the 3x4 patch (rows pr..pr+2, cols pc0..pc0+3)
  int poff[3][4];
#pragma unroll
  for (int dr = 0; dr < 3; dr++)
#pragma unroll
    for (int dc = 0; dc < 4; dc++)
      poff[dr][dc] = ((pr + dr) * HW_HALO + pc0 + dc) * PSTRIDE;

  float4 vals0[3], vals1[3];
  float sum0 = 0.f, sum1 = 0.f;
#pragma unroll
  for (int j = 0; j < 3; j++) {
    int ch = j * 4 + sub;
    float4 q[3][4];
#pragma unroll
    for (int dr = 0; dr < 3; dr++)
#pragma unroll
      for (int dc = 0; dc < 4; dc++) q[dr][dc] = tile[poff[dr][dc] + ch];

    float4 val0, val1;
#define COMP(f)                                                                \
    {                                                                          \
      float s0_ = wt0[0] * q[0][0].f + wt0[1] * q[0][1].f + wt0[2] * q[0][2].f \
                + wt0[3] * q[1][0].f + wt0[4] * q[1][1].f + wt0[5] * q[1][2].f \
                + wt0[6] * q[2][0].f + wt0[7] * q[2][1].f + wt0[8] * q[2][2].f;\
      float v00 = q[2][1].f - q[1][1].f + dld0;                                \
      float v10 = q[1][2].f - q[1][1].f + dlr0;                                \
      float vv0 = s0_ + 0.5f * (ha0 * v00 * v00 + hc0 * v10 * v10) +           \
                  hb0 * (v00 * v10);                                           \
      val0.f = vv0; sum0 += vv0;                                               \
      float s1_ = wt1[0] * q[0][1].f + wt1[1] * q[0][2].f + wt1[2] * q[0][3].f \
                + wt1[3] * q[1][1].f + wt1[4] * q[1][2].f + wt1[5] * q[1][3].f \
                + wt1[6] * q[2][1].f + wt1[7] * q[2][2].f + wt1[8] * q[2][3].f;\
      float v01 = q[2][2].f - q[1][2].f + dld1;                                \
      float v11 = q[1][3].f - q[1][2].f + dlr1;                                \
      float vv1 = s1_ + 0.5f * (ha1 * v01 * v01 + hc1 * v11 * v11) +           \
                  hb1 * (v01 * v11);                                           \
      val1.f = vv1; sum1 += vv1;                                               \
    }
    COMP(x) COMP(y) COMP(z) COMP(w)
#undef COMP
    vals0[j] = val0;
    vals1[j] = val1;
  }

  // channel mean across the 4-thread quad (48 channels per pixel)
  sum0 += __shfl_xor(sum0, 1); sum0 += __shfl_xor(sum0, 2);
  sum1 += __shfl_xor(sum1, 1); sum1 += __shfl_xor(sum1, 2);
  float mean0 = sum0 * (1.0f / 48.0f);
  float mean1 = sum1 * (1.0f / 48.0f);

  // centers re-read from LDS (saves 24 VGPRs vs holding them live)
  int cen0 = lc0 * PSTRIDE;                   // px0 center halo offset
  float4* op0 = (float4*)(xn + (size_t)pix0 * NCH);
  float4* op1 = op0 + 12;
#pragma unroll
  for (int j = 0; j < 3; j++) {
    int ch = j * 4 + sub;
    float4 c0 = tile[cen0 + ch];
    float4 c1 = tile[cen0 + PSTRIDE + ch];
    float4 r0, r1;
    r0.x = c0.x + 0.2f * fminf(fmaxf(vals0[j].x - mean0, -1e8f), 1e8f);
    r0.y = c0.y + 0.2f * fminf(fmaxf(vals0[j].y - mean0, -1e8f), 1e8f);
    r0.z = c0.z + 0.2f * fminf(fmaxf(vals0[j].z - mean0, -1e8f), 1e8f);
    r0.w = c0.w + 0.2f * fminf(fmaxf(vals0[j].w - mean0, -1e8f), 1e8f);
    r1.x = c1.x + 0.2f * fminf(fmaxf(vals1[j].x - mean1, -1e8f), 1e8f);
    r1.y = c1.y + 0.2f * fminf(fmaxf(vals1[j].y - mean1, -1e8f), 1e8f);
    r1.z = c1.z + 0.2f * fminf(fmaxf(vals1[j].z - mean1, -1e8f), 1e8f);
    r1.w = c1.w + 0.2f * fminf(fmaxf(vals1[j].w - mean1, -1e8f), 1e8f);
    op0[ch] = r0;
    op1[ch] = r1;
  }
}

// ---------------------------------------------------------------------------
// Host launcher.  inputs: v (H,W,48), Dt (H,W,3), dg (H,W,1), hinv (H,W,3)
// ws layout: A[12*HW packed] | xbuf[HW*48]   (~63 MB)
// ping-pong: v -> out -> ws -> out -> ws -> out  (5 steps)
// ---------------------------------------------------------------------------
extern "C" void kernel_launch(void* const* d_in, const int* in_sizes, int n_in,
                              void* d_out, int out_size, void* d_ws, size_t ws_size,
                              hipStream_t stream) {
  const float* v    = (const float*)d_in[0];
  const float* Dt   = (const float*)d_in[1];
  const float* dg   = (const float*)d_in[2];
  const float* hinv = (const float*)d_in[3];
  float* out = (float*)d_out;

  float* A    = (float*)d_ws;
  float* xbuf = A + (size_t)ASTRIDE * HWPIX;

  compute_A_kernel<<<dim3(HWPIX / 256), dim3(256), 0, stream>>>(Dt, dg, A);

  const float* cur = v;
  float* nxt = out;
  for (int s = 0; s < 5; s++) {
    step_fused_kernel<<<dim3(HWPIX / 128), dim3(256), 0, stream>>>(cur, A, hinv, nxt);
    if (s == 0) {
      cur = out;
      nxt = xbuf;
    } else {
      float* t = (float*)cur;
      cur = nxt;
      nxt = t;
    }
  }
}